// Round 10
// baseline (319.067 us; speedup 1.0000x reference)
//
#include <hip/hip_runtime.h>
#include <hip/hip_fp16.h>
#include <cmath>

#define NLVL 16
#define QUAD_LVLS 13            // levels [0,13): row-pair quad entries (8B); [13,16): plain (4B)
#define TSIZE (1u << 19)
#define HMASK ((1u << 19) - 1u)
#define PRIME1 2654435761u
#define FSCALE 1024.0f          // 2^10: keeps |v|<=1e-4 in fp16-normal range
#define FINV   (1.0f/1024.0f)   // exact power of 2 -> no extra rounding

typedef float f32x4 __attribute__((ext_vector_type(4)));
typedef unsigned int       u32;
typedef unsigned long long u64;

struct Params {
    float rf[NLVL];
    int   ri[NLVL];
    int   base[NLVL];     // u32 index of level's table inside ws
    int   stride[NLVL];   // entries per row = ri+2 (pad entry keeps edge loads in-bounds)
};

__device__ __forceinline__ float2 h2f(u32 u) {
    __half2 h; __builtin_memcpy(&h, &u, 4);
    return __half22float2(h);
}

__device__ __forceinline__ u32 packh(float2 v) {
    return (u32)__half_as_ushort(__float2half_rn(v.x * FSCALE))
         | ((u32)__half_as_ushort(__float2half_rn(v.y * FSCALE)) << 16);
}

// Pre-pass: hybrid dense table, sized to FIT the 4MiB per-XCD L2 (3.58 MB).
//  - levels 0..12: ROW-PAIR QUAD entries entry(r,cx)={cell(cx,r),cell(cx,r+1)}
//    (8B) -> full bilinear quad is ONE 16B load (one L2 line).
//  - levels 13..15: plain 4B entries -> two 8B row loads, no duplication so
//    the total stays L2-resident (r6's 5.7MB all-quad thrashed: FETCH 96MB;
//    r8/r9's 3.58MB hybrid: FETCH ~20MB).
__global__ __launch_bounds__(256) void build_dense_hyb(
    const float2* __restrict__ emb, u32* __restrict__ dense, Params p)
{
    const int l  = blockIdx.y;
    const int r  = blockIdx.x;
    const int ri = p.ri[l];
    if (r > ri) return;
    const u64* tab = (const u64*)(emb + (size_t)l * TSIZE);
    if (l < QUAD_LVLS) {
        const unsigned hy0 = (unsigned)r * PRIME1;
        const unsigned hy1 = (unsigned)min(r + 1, ri) * PRIME1;
        uint2* drow = (uint2*)(dense + p.base[l]) + (size_t)r * p.stride[l];
        for (int cx = threadIdx.x; cx <= ri; cx += 256) {
            u64 raw0 = __builtin_nontemporal_load(tab + (((unsigned)cx ^ hy0) & HMASK));
            u64 raw1 = __builtin_nontemporal_load(tab + (((unsigned)cx ^ hy1) & HMASK));
            float2 v0, v1;
            __builtin_memcpy(&v0, &raw0, 8);
            __builtin_memcpy(&v1, &raw1, 8);
            uint2 e; e.x = packh(v0); e.y = packh(v1);
            drow[cx] = e;
        }
    } else {
        const unsigned hy = (unsigned)r * PRIME1;
        u32* drow = dense + p.base[l] + (size_t)r * p.stride[l];
        for (int cx = threadIdx.x; cx <= ri; cx += 256) {
            u64 raw = __builtin_nontemporal_load(tab + (((unsigned)cx ^ hy) & HMASK));
            float2 v; __builtin_memcpy(&v, &raw, 8);
            drow[cx] = packh(v);
        }
    }
}

// Main: ZERO-BARRIER version of r9. Each wave transposes its own 64 points in
// a wave-PRIVATE 4KB LDS slice (4 waves x 4KB = same 16KB total). Same-wave DS
// ops execute in order -> lgkmcnt discipline replaces all 3 __syncthreads of
// r9; waves run fully independently (no 4-wave convergence stalls between
// gather/blend/write phases). Half-1 gathers issue under half-0's write-out
// (r9's proven overlap). Hybrid table: 11 fine L2 lines/pt. Write path keeps
// r2's 64B-granule coalesced nt stores (compulsory ~129MB).
__global__ __launch_bounds__(256, 8) void hash_embed_hyb3(
    const float2* __restrict__ x,
    const u32*    __restrict__ dense,
    float*        __restrict__ out,
    Params p, int n)
{
    __shared__ float lds[16 * 256];   // 16 KiB = 4 waves x 1024 floats (private)
    const int tid = threadIdx.x;
    const int w   = tid >> 6;         // wave id
    const int ln  = tid & 63;         // lane
    const int i = blockIdx.x * 256 + tid;
    float2 xy = make_float2(0.f, 0.f);
    if (i < n) {
        u64 raw = __builtin_nontemporal_load((const u64*)(x + i));
        __builtin_memcpy(&xy, &raw, 8);
    }

    const int wbase = w * 1024;                               // wave's LDS slice
    const long long ptw = (long long)blockIdx.x * 256 + w * 64;  // wave's first point

    // ---------------- half 0: levels 0..7 (all quad) ----------------
    uint4 q0[8]; float a_w0[8], a_w1[8]; u32 em0 = 0;
    #pragma unroll
    for (int j = 0; j < 8; ++j) {
        const float rf = p.rf[j];
        const int ri = p.ri[j];
        const float px = xy.x * rf, py = xy.y * rf;
        const float fx = floorf(px), fy = floorf(py);
        a_w0[j] = px - fx;
        a_w1[j] = py - fy;
        const int tx = (int)fx, ty = (int)fy;
        const int cx0 = min(tx, ri);
        const int cy0 = min(ty, ri);
        em0 |= (u32)(cx0 == ri) << j;          // then cx1==cx0 (clip)
        const uint2* a = (const uint2*)(dense + p.base[j]) + cy0 * p.stride[j] + cx0;
        __builtin_memcpy(&q0[j], a, 16);       // 8B-aligned dwordx4
    }
    // blend h0 (reference fp32 order) -> wave-private LDS
    #pragma unroll
    for (int j = 0; j < 8; ++j) {
        const float w0 = a_w0[j], w1 = a_w1[j];
        const float u0 = 1.f - w0, u1 = 1.f - w1;
        const bool ed = (em0 >> j) & 1u;
        const float2 e00 = h2f(q0[j].x);       // quad: x=e00 y=e10 z=e01 w=e11
        const float2 e10 = h2f(q0[j].y);
        const float2 e01 = h2f(ed ? q0[j].x : q0[j].z);
        const float2 e11 = h2f(ed ? q0[j].y : q0[j].w);
        const float g0 = ((e00.x*u0 + e01.x*w0)*u1 + (e10.x*u0 + e11.x*w0)*w1) * FINV;
        const float g1 = ((e00.y*u0 + e01.y*w0)*u1 + (e10.y*u0 + e11.y*w0)*w1) * FINV;
        const int idx = wbase + j * 128 + ((2 * ln) ^ (j << 1));  // bank swizzle
        lds[idx]     = g0;
        lds[idx + 1] = g1;
    }

    // ------------- half 1: issue gathers now (hide under h0 write-out) -------------
    uint4 q1[5]; uint2 pa[3], pb[3]; float b_w0[8], b_w1[8]; u32 em1 = 0;
    #pragma unroll
    for (int j = 0; j < 8; ++j) {
        const int l = 8 + j;
        const float rf = p.rf[l];
        const int ri = p.ri[l];
        const float px = xy.x * rf, py = xy.y * rf;
        const float fx = floorf(px), fy = floorf(py);
        b_w0[j] = px - fx;
        b_w1[j] = py - fy;
        const int tx = (int)fx, ty = (int)fy;
        const int cx0 = min(tx, ri);
        const int cy0 = min(ty, ri);
        em1 |= (u32)(cx0 == ri) << j;
        if (l < QUAD_LVLS) {
            const uint2* a = (const uint2*)(dense + p.base[l]) + cy0 * p.stride[l] + cx0;
            __builtin_memcpy(&q1[j], a, 16);
        } else {
            const int m = j - 5;               // l = 13..15
            const int cy1 = min(ty + 1, ri);
            const u32* tab = dense + p.base[l];
            __builtin_memcpy(&pa[m], tab + cy0 * p.stride[l] + cx0, 8);
            __builtin_memcpy(&pb[m], tab + cy1 * p.stride[l] + cx0, 8);
        }
    }

    // ------------- h0 transpose-read + coalesced nt store (no barrier!) -------------
    #pragma unroll
    for (int it = 0; it < 4; ++it) {
        const int k  = (it * 64 + ln) * 4;     // 0..1023 float idx in wave half-chunk
        const int pp = k >> 4;                 // point within wave (0..63)
        const int kk = k & 15;                 // {0,4,8,12}
        const int j0 = kk >> 1;                // {0,2,4,6}
        const long long pt = ptw + pp;
        if (pt < n) {
            const int s0 = wbase + j0 * 128       + ((2 * pp) ^ (j0 << 1));
            const int s1 = wbase + (j0 + 1) * 128 + ((2 * pp) ^ ((j0 + 1) << 1));
            f32x4 v;
            v.x = lds[s0]; v.y = lds[s0 + 1];
            v.z = lds[s1]; v.w = lds[s1 + 1];
            __builtin_nontemporal_store(v, (f32x4*)(out + pt * 32 + kk));
        }
    }

    // WAR fence: h1 ds_writes must not pass h0 ds_reads (same-wave DS ops are
    // in-order in HW; this pins the compiler's ordering too)
    asm volatile("s_waitcnt lgkmcnt(0)" ::: "memory");

    // ------------- blend h1 -> wave-private LDS -------------
    #pragma unroll
    for (int j = 0; j < 8; ++j) {
        const int l = 8 + j;
        const float w0 = b_w0[j], w1 = b_w1[j];
        const float u0 = 1.f - w0, u1 = 1.f - w1;
        const bool ed = (em1 >> j) & 1u;
        float2 e00, e01, e10, e11;
        if (l < QUAD_LVLS) {                   // quad entry
            e00 = h2f(q1[j].x);
            e10 = h2f(q1[j].y);
            e01 = h2f(ed ? q1[j].x : q1[j].z);
            e11 = h2f(ed ? q1[j].y : q1[j].w);
        } else {                               // plain rows: a={e00,e01} b={e10,e11}
            const int m = j - 5;
            e00 = h2f(pa[m].x);
            e01 = h2f(ed ? pa[m].x : pa[m].y);
            e10 = h2f(pb[m].x);
            e11 = h2f(ed ? pb[m].x : pb[m].y);
        }
        const float g0 = ((e00.x*u0 + e01.x*w0)*u1 + (e10.x*u0 + e11.x*w0)*w1) * FINV;
        const float g1 = ((e00.y*u0 + e01.y*w0)*u1 + (e10.y*u0 + e11.y*w0)*w1) * FINV;
        const int idx = wbase + j * 128 + ((2 * ln) ^ (j << 1));
        lds[idx]     = g0;
        lds[idx + 1] = g1;
    }

    // ------------- h1 transpose-read + coalesced nt store -------------
    #pragma unroll
    for (int it = 0; it < 4; ++it) {
        const int k  = (it * 64 + ln) * 4;
        const int pp = k >> 4;
        const int kk = k & 15;
        const int j0 = kk >> 1;
        const long long pt = ptw + pp;
        if (pt < n) {
            const int s0 = wbase + j0 * 128       + ((2 * pp) ^ (j0 << 1));
            const int s1 = wbase + (j0 + 1) * 128 + ((2 * pp) ^ ((j0 + 1) << 1));
            f32x4 v;
            v.x = lds[s0]; v.y = lds[s0 + 1];
            v.z = lds[s1]; v.w = lds[s1 + 1];
            __builtin_nontemporal_store(v, (f32x4*)(out + pt * 32 + 16 + kk));
        }
    }
}

// Fallback: direct f32 hash gathers, used only if ws is too small.
__global__ __launch_bounds__(256) void hash_embed_direct(
    const float2* __restrict__ x,
    const float2* __restrict__ emb,
    float* __restrict__ out,
    Params p, int n)
{
    __shared__ float2 lds[NLVL * 256];
    const int tid = threadIdx.x;
    const int i = blockIdx.x * 256 + tid;
    float2 xy = make_float2(0.f, 0.f);
    if (i < n) xy = x[i];

    #pragma unroll
    for (int half = 0; half < 2; ++half) {
        float2 f[32];
        float w0v[8], w1v[8];
        #pragma unroll
        for (int j = 0; j < 8; ++j) {
            const int l = half * 8 + j;
            const float rf = p.rf[l];
            const int ri = p.ri[l];
            const float px = xy.x * rf, py = xy.y * rf;
            const float fx = floorf(px), fy = floorf(py);
            w0v[j] = px - fx;
            w1v[j] = py - fy;
            const int tx = (int)fx, ty = (int)fy;
            const unsigned cx0 = (unsigned)min(tx, ri);
            const unsigned cy0 = (unsigned)min(ty, ri);
            const unsigned cx1 = (unsigned)min(tx + 1, ri);
            const unsigned cy1 = (unsigned)min(ty + 1, ri);
            const unsigned hy0 = cy0 * PRIME1;
            const unsigned hy1 = cy1 * PRIME1;
            const float2* tab = emb + (size_t)l * TSIZE;
            f[j*4+0] = tab[(cx0 ^ hy0) & HMASK];
            f[j*4+1] = tab[(cx1 ^ hy0) & HMASK];
            f[j*4+2] = tab[(cx0 ^ hy1) & HMASK];
            f[j*4+3] = tab[(cx1 ^ hy1) & HMASK];
        }
        #pragma unroll
        for (int j = 0; j < 8; ++j) {
            const int l = half * 8 + j;
            const float w0 = w0v[j], w1 = w1v[j];
            const float u0 = 1.f - w0, u1 = 1.f - w1;
            const float2 f0 = f[j*4+0], f1 = f[j*4+1], f2 = f[j*4+2], f3 = f[j*4+3];
            const float g0 = (f0.x*u0 + f1.x*w0)*u1 + (f2.x*u0 + f3.x*w0)*w1;
            const float g1 = (f0.y*u0 + f1.y*w0)*u1 + (f2.y*u0 + f3.y*w0)*w1;
            lds[l * 256 + tid] = make_float2(g0, g1);
        }
    }
    __syncthreads();

    const float* lf = (const float*)lds;
    const long long total = (long long)n * 32;
    const long long base = (long long)blockIdx.x * 8192;
    #pragma unroll
    for (int it = 0; it < 8; ++it) {
        const int k = (it * 256 + tid) * 4;
        if (base + k < total) {
            const int p2 = k >> 5;
            const int l0 = (k & 31) >> 1;
            float4 v;
            v.x = lf[(l0 * 256 + p2) * 2 + 0];
            v.y = lf[(l0 * 256 + p2) * 2 + 1];
            v.z = lf[((l0 + 1) * 256 + p2) * 2 + 0];
            v.w = lf[((l0 + 1) * 256 + p2) * 2 + 1];
            *(float4*)(out + base + k) = v;
        }
    }
}

extern "C" void kernel_launch(void* const* d_in, const int* in_sizes, int n_in,
                              void* d_out, int out_size, void* d_ws, size_t ws_size,
                              hipStream_t stream) {
    const float2* x = (const float2*)d_in[0];
    const float2* emb = (const float2*)d_in[1];
    float* out = (float*)d_out;
    const int n = in_sizes[0] / 2;

    // numpy-exact per-level resolutions (ulp-sensitive floors at l=3,6,9,...)
    Params p;
    int off = 0;   // u32 units; quad levels have even bases (8B alignment)
    const double b = std::exp((std::log(512.0) - std::log(16.0)) / 15.0);
    for (int l = 0; l < NLVL; ++l) {
        const double r = std::floor(16.0 * std::pow(b, (double)l));
        p.rf[l] = (float)r;
        p.ri[l] = (int)r;
        p.stride[l] = p.ri[l] + 2;
        p.base[l] = off;
        const int cells = (p.ri[l] + 1) * (p.ri[l] + 2);
        off += (l < QUAD_LVLS) ? cells * 2 : cells;
    }
    const size_t need = (size_t)off * sizeof(u32);   // ~3.58 MiB (fits 4MiB XCD L2)

    const int grid = (n + 255) / 256;
    if (ws_size >= need) {
        build_dense_hyb<<<dim3(513, 16), 256, 0, stream>>>(emb, (u32*)d_ws, p);
        hash_embed_hyb3<<<grid, 256, 0, stream>>>(x, (const u32*)d_ws, out, p, n);
    } else {
        hash_embed_direct<<<grid, 256, 0, stream>>>(x, emb, out, p, n);
    }
}

// Round 11
// 230.167 us; speedup vs baseline: 1.3862x; 1.3862x over previous
//
#include <hip/hip_runtime.h>
#include <hip/hip_fp16.h>
#include <cmath>

#define NLVL 16
#define QUAD_LVLS 13            // levels [0,13): row-pair quad entries (8B); [13,16): plain (4B)
#define TSIZE (1u << 19)
#define HMASK ((1u << 19) - 1u)
#define PRIME1 2654435761u
#define FSCALE 1024.0f          // 2^10: keeps |v|<=1e-4 in fp16-normal range
#define FINV   (1.0f/1024.0f)   // exact power of 2 -> no extra rounding

typedef float f32x4 __attribute__((ext_vector_type(4)));
typedef unsigned int       u32;
typedef unsigned long long u64;

struct Params {
    float rf[NLVL];
    int   ri[NLVL];
    int   base[NLVL];     // u32 index of level's table inside ws
    int   stride[NLVL];   // entries per row = ri+2 (pad entry keeps edge loads in-bounds)
};

__device__ __forceinline__ float2 h2f(u32 u) {
    __half2 h; __builtin_memcpy(&h, &u, 4);
    return __half22float2(h);
}

__device__ __forceinline__ u32 packh(float2 v) {
    return (u32)__half_as_ushort(__float2half_rn(v.x * FSCALE))
         | ((u32)__half_as_ushort(__float2half_rn(v.y * FSCALE)) << 16);
}

// Pre-pass: hybrid dense table, sized to FIT the 4MiB per-XCD L2 (3.58 MB).
//  - levels 0..12: ROW-PAIR QUAD entries entry(r,cx)={cell(cx,r),cell(cx,r+1)}
//    (8B) -> full bilinear quad is ONE 16B load (one L2 line).
//  - levels 13..15: plain 4B entries -> two 8B row loads, no duplication so
//    the total stays L2-resident (r6's 5.7MB all-quad thrashed: FETCH 96MB;
//    r8/r9's 3.58MB hybrid: FETCH ~20MB).
__global__ __launch_bounds__(256) void build_dense_hyb(
    const float2* __restrict__ emb, u32* __restrict__ dense, Params p)
{
    const int l  = blockIdx.y;
    const int r  = blockIdx.x;
    const int ri = p.ri[l];
    if (r > ri) return;
    const u64* tab = (const u64*)(emb + (size_t)l * TSIZE);
    if (l < QUAD_LVLS) {
        const unsigned hy0 = (unsigned)r * PRIME1;
        const unsigned hy1 = (unsigned)min(r + 1, ri) * PRIME1;
        uint2* drow = (uint2*)(dense + p.base[l]) + (size_t)r * p.stride[l];
        for (int cx = threadIdx.x; cx <= ri; cx += 256) {
            u64 raw0 = __builtin_nontemporal_load(tab + (((unsigned)cx ^ hy0) & HMASK));
            u64 raw1 = __builtin_nontemporal_load(tab + (((unsigned)cx ^ hy1) & HMASK));
            float2 v0, v1;
            __builtin_memcpy(&v0, &raw0, 8);
            __builtin_memcpy(&v1, &raw1, 8);
            uint2 e; e.x = packh(v0); e.y = packh(v1);
            drow[cx] = e;
        }
    } else {
        const unsigned hy = (unsigned)r * PRIME1;
        u32* drow = dense + p.base[l] + (size_t)r * p.stride[l];
        for (int cx = threadIdx.x; cx <= ri; cx += 256) {
            u64 raw = __builtin_nontemporal_load(tab + (((unsigned)cx ^ hy) & HMASK));
            float2 v; __builtin_memcpy(&v, &raw, 8);
            drow[cx] = packh(v);
        }
    }
}

// Main: ZERO-BARRIER. Each wave transposes its own 64 points in a wave-PRIVATE
// 4KB LDS slice (4 waves x 4KB = 16KB total). Same-wave DS ops execute in
// order -> no __syncthreads needed anywhere; waves run fully independently.
// Half-1 gathers issue under half-0's write-out (r9's proven overlap).
// Hybrid table: 11 fine L2 lines/pt. Write path keeps r2's 64B-granule
// coalesced nt stores (compulsory ~129MB).
// NOTE: default launch bounds! r10's (256,8) forced 32 VGPR -> ~360MB scratch
// spill traffic (FETCH 227MB / WRITE 281MB), main 180us. Peak live state here
// is ~60-70 VGPR; let the allocator have it.
__global__ __launch_bounds__(256) void hash_embed_hyb3(
    const float2* __restrict__ x,
    const u32*    __restrict__ dense,
    float*        __restrict__ out,
    Params p, int n)
{
    __shared__ float lds[16 * 256];   // 16 KiB = 4 waves x 1024 floats (private)
    const int tid = threadIdx.x;
    const int w   = tid >> 6;         // wave id
    const int ln  = tid & 63;         // lane
    const int i = blockIdx.x * 256 + tid;
    float2 xy = make_float2(0.f, 0.f);
    if (i < n) {
        u64 raw = __builtin_nontemporal_load((const u64*)(x + i));
        __builtin_memcpy(&xy, &raw, 8);
    }

    const int wbase = w * 1024;                               // wave's LDS slice
    const long long ptw = (long long)blockIdx.x * 256 + w * 64;  // wave's first point

    // ---------------- half 0: levels 0..7 (all quad) ----------------
    uint4 q0[8]; float a_w0[8], a_w1[8]; u32 em0 = 0;
    #pragma unroll
    for (int j = 0; j < 8; ++j) {
        const float rf = p.rf[j];
        const int ri = p.ri[j];
        const float px = xy.x * rf, py = xy.y * rf;
        const float fx = floorf(px), fy = floorf(py);
        a_w0[j] = px - fx;
        a_w1[j] = py - fy;
        const int tx = (int)fx, ty = (int)fy;
        const int cx0 = min(tx, ri);
        const int cy0 = min(ty, ri);
        em0 |= (u32)(cx0 == ri) << j;          // then cx1==cx0 (clip)
        const uint2* a = (const uint2*)(dense + p.base[j]) + cy0 * p.stride[j] + cx0;
        __builtin_memcpy(&q0[j], a, 16);       // 8B-aligned dwordx4
    }
    // blend h0 (reference fp32 order) -> wave-private LDS
    #pragma unroll
    for (int j = 0; j < 8; ++j) {
        const float w0 = a_w0[j], w1 = a_w1[j];
        const float u0 = 1.f - w0, u1 = 1.f - w1;
        const bool ed = (em0 >> j) & 1u;
        const float2 e00 = h2f(q0[j].x);       // quad: x=e00 y=e10 z=e01 w=e11
        const float2 e10 = h2f(q0[j].y);
        const float2 e01 = h2f(ed ? q0[j].x : q0[j].z);
        const float2 e11 = h2f(ed ? q0[j].y : q0[j].w);
        const float g0 = ((e00.x*u0 + e01.x*w0)*u1 + (e10.x*u0 + e11.x*w0)*w1) * FINV;
        const float g1 = ((e00.y*u0 + e01.y*w0)*u1 + (e10.y*u0 + e11.y*w0)*w1) * FINV;
        const int idx = wbase + j * 128 + ((2 * ln) ^ (j << 1));  // bank swizzle
        lds[idx]     = g0;
        lds[idx + 1] = g1;
    }

    // ------------- half 1: issue gathers now (hide under h0 write-out) -------------
    uint4 q1[5]; uint2 pa[3], pb[3]; float b_w0[8], b_w1[8]; u32 em1 = 0;
    #pragma unroll
    for (int j = 0; j < 8; ++j) {
        const int l = 8 + j;
        const float rf = p.rf[l];
        const int ri = p.ri[l];
        const float px = xy.x * rf, py = xy.y * rf;
        const float fx = floorf(px), fy = floorf(py);
        b_w0[j] = px - fx;
        b_w1[j] = py - fy;
        const int tx = (int)fx, ty = (int)fy;
        const int cx0 = min(tx, ri);
        const int cy0 = min(ty, ri);
        em1 |= (u32)(cx0 == ri) << j;
        if (l < QUAD_LVLS) {
            const uint2* a = (const uint2*)(dense + p.base[l]) + cy0 * p.stride[l] + cx0;
            __builtin_memcpy(&q1[j], a, 16);
        } else {
            const int m = j - 5;               // l = 13..15
            const int cy1 = min(ty + 1, ri);
            const u32* tab = dense + p.base[l];
            __builtin_memcpy(&pa[m], tab + cy0 * p.stride[l] + cx0, 8);
            __builtin_memcpy(&pb[m], tab + cy1 * p.stride[l] + cx0, 8);
        }
    }

    // ------------- h0 transpose-read + coalesced nt store (no barrier!) -------------
    #pragma unroll
    for (int it = 0; it < 4; ++it) {
        const int k  = (it * 64 + ln) * 4;     // 0..1023 float idx in wave half-chunk
        const int pp = k >> 4;                 // point within wave (0..63)
        const int kk = k & 15;                 // {0,4,8,12}
        const int j0 = kk >> 1;                // {0,2,4,6}
        const long long pt = ptw + pp;
        if (pt < n) {
            const int s0 = wbase + j0 * 128       + ((2 * pp) ^ (j0 << 1));
            const int s1 = wbase + (j0 + 1) * 128 + ((2 * pp) ^ ((j0 + 1) << 1));
            f32x4 v;
            v.x = lds[s0]; v.y = lds[s0 + 1];
            v.z = lds[s1]; v.w = lds[s1 + 1];
            __builtin_nontemporal_store(v, (f32x4*)(out + pt * 32 + kk));
        }
    }

    // WAR fence: h1 ds_writes must not pass h0 ds_reads (same-wave DS ops are
    // in-order in HW; this pins the compiler's ordering too)
    asm volatile("s_waitcnt lgkmcnt(0)" ::: "memory");

    // ------------- blend h1 -> wave-private LDS -------------
    #pragma unroll
    for (int j = 0; j < 8; ++j) {
        const int l = 8 + j;
        const float w0 = b_w0[j], w1 = b_w1[j];
        const float u0 = 1.f - w0, u1 = 1.f - w1;
        const bool ed = (em1 >> j) & 1u;
        float2 e00, e01, e10, e11;
        if (l < QUAD_LVLS) {                   // quad entry
            e00 = h2f(q1[j].x);
            e10 = h2f(q1[j].y);
            e01 = h2f(ed ? q1[j].x : q1[j].z);
            e11 = h2f(ed ? q1[j].y : q1[j].w);
        } else {                               // plain rows: a={e00,e01} b={e10,e11}
            const int m = j - 5;
            e00 = h2f(pa[m].x);
            e01 = h2f(ed ? pa[m].x : pa[m].y);
            e10 = h2f(pb[m].x);
            e11 = h2f(ed ? pb[m].x : pb[m].y);
        }
        const float g0 = ((e00.x*u0 + e01.x*w0)*u1 + (e10.x*u0 + e11.x*w0)*w1) * FINV;
        const float g1 = ((e00.y*u0 + e01.y*w0)*u1 + (e10.y*u0 + e11.y*w0)*w1) * FINV;
        const int idx = wbase + j * 128 + ((2 * ln) ^ (j << 1));
        lds[idx]     = g0;
        lds[idx + 1] = g1;
    }

    // ------------- h1 transpose-read + coalesced nt store -------------
    #pragma unroll
    for (int it = 0; it < 4; ++it) {
        const int k  = (it * 64 + ln) * 4;
        const int pp = k >> 4;
        const int kk = k & 15;
        const int j0 = kk >> 1;
        const long long pt = ptw + pp;
        if (pt < n) {
            const int s0 = wbase + j0 * 128       + ((2 * pp) ^ (j0 << 1));
            const int s1 = wbase + (j0 + 1) * 128 + ((2 * pp) ^ ((j0 + 1) << 1));
            f32x4 v;
            v.x = lds[s0]; v.y = lds[s0 + 1];
            v.z = lds[s1]; v.w = lds[s1 + 1];
            __builtin_nontemporal_store(v, (f32x4*)(out + pt * 32 + 16 + kk));
        }
    }
}

// Fallback: direct f32 hash gathers, used only if ws is too small.
__global__ __launch_bounds__(256) void hash_embed_direct(
    const float2* __restrict__ x,
    const float2* __restrict__ emb,
    float* __restrict__ out,
    Params p, int n)
{
    __shared__ float2 lds[NLVL * 256];
    const int tid = threadIdx.x;
    const int i = blockIdx.x * 256 + tid;
    float2 xy = make_float2(0.f, 0.f);
    if (i < n) xy = x[i];

    #pragma unroll
    for (int half = 0; half < 2; ++half) {
        float2 f[32];
        float w0v[8], w1v[8];
        #pragma unroll
        for (int j = 0; j < 8; ++j) {
            const int l = half * 8 + j;
            const float rf = p.rf[l];
            const int ri = p.ri[l];
            const float px = xy.x * rf, py = xy.y * rf;
            const float fx = floorf(px), fy = floorf(py);
            w0v[j] = px - fx;
            w1v[j] = py - fy;
            const int tx = (int)fx, ty = (int)fy;
            const unsigned cx0 = (unsigned)min(tx, ri);
            const unsigned cy0 = (unsigned)min(ty, ri);
            const unsigned cx1 = (unsigned)min(tx + 1, ri);
            const unsigned cy1 = (unsigned)min(ty + 1, ri);
            const unsigned hy0 = cy0 * PRIME1;
            const unsigned hy1 = cy1 * PRIME1;
            const float2* tab = emb + (size_t)l * TSIZE;
            f[j*4+0] = tab[(cx0 ^ hy0) & HMASK];
            f[j*4+1] = tab[(cx1 ^ hy0) & HMASK];
            f[j*4+2] = tab[(cx0 ^ hy1) & HMASK];
            f[j*4+3] = tab[(cx1 ^ hy1) & HMASK];
        }
        #pragma unroll
        for (int j = 0; j < 8; ++j) {
            const int l = half * 8 + j;
            const float w0 = w0v[j], w1 = w1v[j];
            const float u0 = 1.f - w0, u1 = 1.f - w1;
            const float2 f0 = f[j*4+0], f1 = f[j*4+1], f2 = f[j*4+2], f3 = f[j*4+3];
            const float g0 = (f0.x*u0 + f1.x*w0)*u1 + (f2.x*u0 + f3.x*w0)*w1;
            const float g1 = (f0.y*u0 + f1.y*w0)*u1 + (f2.y*u0 + f3.y*w0)*w1;
            lds[l * 256 + tid] = make_float2(g0, g1);
        }
    }
    __syncthreads();

    const float* lf = (const float*)lds;
    const long long total = (long long)n * 32;
    const long long base = (long long)blockIdx.x * 8192;
    #pragma unroll
    for (int it = 0; it < 8; ++it) {
        const int k = (it * 256 + tid) * 4;
        if (base + k < total) {
            const int p2 = k >> 5;
            const int l0 = (k & 31) >> 1;
            float4 v;
            v.x = lf[(l0 * 256 + p2) * 2 + 0];
            v.y = lf[(l0 * 256 + p2) * 2 + 1];
            v.z = lf[((l0 + 1) * 256 + p2) * 2 + 0];
            v.w = lf[((l0 + 1) * 256 + p2) * 2 + 1];
            *(float4*)(out + base + k) = v;
        }
    }
}

extern "C" void kernel_launch(void* const* d_in, const int* in_sizes, int n_in,
                              void* d_out, int out_size, void* d_ws, size_t ws_size,
                              hipStream_t stream) {
    const float2* x = (const float2*)d_in[0];
    const float2* emb = (const float2*)d_in[1];
    float* out = (float*)d_out;
    const int n = in_sizes[0] / 2;

    // numpy-exact per-level resolutions (ulp-sensitive floors at l=3,6,9,...)
    Params p;
    int off = 0;   // u32 units; quad levels have even bases (8B alignment)
    const double b = std::exp((std::log(512.0) - std::log(16.0)) / 15.0);
    for (int l = 0; l < NLVL; ++l) {
        const double r = std::floor(16.0 * std::pow(b, (double)l));
        p.rf[l] = (float)r;
        p.ri[l] = (int)r;
        p.stride[l] = p.ri[l] + 2;
        p.base[l] = off;
        const int cells = (p.ri[l] + 1) * (p.ri[l] + 2);
        off += (l < QUAD_LVLS) ? cells * 2 : cells;
    }
    const size_t need = (size_t)off * sizeof(u32);   // ~3.58 MiB (fits 4MiB XCD L2)

    const int grid = (n + 255) / 256;
    if (ws_size >= need) {
        build_dense_hyb<<<dim3(513, 16), 256, 0, stream>>>(emb, (u32*)d_ws, p);
        hash_embed_hyb3<<<grid, 256, 0, stream>>>(x, (const u32*)d_ws, out, p, n);
    } else {
        hash_embed_direct<<<grid, 256, 0, stream>>>(x, emb, out, p, n);
    }
}